// Round 1
// baseline (143536.133 us; speedup 1.0000x reference)
//
#include <hip/hip_runtime.h>
#include <math.h>

#define BATCH 16
#define TLEN 4096
#define KDIM 512      // Din == Hdim == 512
#define G3 1536       // 3*H
#define GRID_REC 128
#define SU 4          // hidden units per rec block (SU*GRID_REC == 512)

// ---------------------------------------------------------------------------
// GEMM: C[M,N] = A[M,K] @ W[N,K]^T + bias[N], K=512, M=65536, N=1536
// 128x128 block tile, 8x8 micro-tile per thread, 256 threads.
// ---------------------------------------------------------------------------
__global__ __launch_bounds__(256)
void gemm_nt_bias(const float* __restrict__ A, const float* __restrict__ W,
                  const float* __restrict__ bias, float* __restrict__ C,
                  int M, int N) {
  const int K = KDIM;
  __shared__ float As[16][132];
  __shared__ float Bs[16][132];
  int tid = threadIdx.x;
  int tx = tid & 15, ty = tid >> 4;
  int bx = blockIdx.x, by = blockIdx.y;
  const float* Ab = A + (size_t)by * 128 * K;
  const float* Wb = W + (size_t)bx * 128 * K;

  float acc[8][8];
#pragma unroll
  for (int i = 0; i < 8; i++)
#pragma unroll
    for (int j = 0; j < 8; j++) acc[i][j] = 0.f;

  for (int kk = 0; kk < K; kk += 16) {
    __syncthreads();
#pragma unroll
    for (int i = 0; i < 2; i++) {
      int task = tid + i * 256;      // 512 float4 loads per tile per matrix
      int kc = task & 3;             // which float4 within the 16-wide k-slab
      int m  = task >> 2;            // 0..127 row within tile
      float4 va = *(const float4*)(Ab + (size_t)m * K + kk + kc * 4);
      As[kc*4+0][m] = va.x; As[kc*4+1][m] = va.y;
      As[kc*4+2][m] = va.z; As[kc*4+3][m] = va.w;
      float4 vb = *(const float4*)(Wb + (size_t)m * K + kk + kc * 4);
      Bs[kc*4+0][m] = vb.x; Bs[kc*4+1][m] = vb.y;
      Bs[kc*4+2][m] = vb.z; Bs[kc*4+3][m] = vb.w;
    }
    __syncthreads();
#pragma unroll
    for (int k = 0; k < 16; k++) {
      float4 a0 = *(const float4*)&As[k][ty * 4];
      float4 a1 = *(const float4*)&As[k][64 + ty * 4];
      float4 b0 = *(const float4*)&Bs[k][tx * 4];
      float4 b1 = *(const float4*)&Bs[k][64 + tx * 4];
      float av[8] = {a0.x, a0.y, a0.z, a0.w, a1.x, a1.y, a1.z, a1.w};
      float bv[8] = {b0.x, b0.y, b0.z, b0.w, b1.x, b1.y, b1.z, b1.w};
#pragma unroll
      for (int i = 0; i < 8; i++)
#pragma unroll
        for (int j = 0; j < 8; j++) acc[i][j] += av[i] * bv[j];
    }
  }

#pragma unroll
  for (int hi = 0; hi < 2; hi++)
#pragma unroll
    for (int i = 0; i < 4; i++) {
      int m = by * 128 + hi * 64 + ty * 4 + i;
#pragma unroll
      for (int hj = 0; hj < 2; hj++) {
        int n = bx * 128 + hj * 64 + tx * 4;
        float4 bb = *(const float4*)(bias + n);
        float4 v;
        v.x = acc[hi*4+i][hj*4+0] + bb.x;
        v.y = acc[hi*4+i][hj*4+1] + bb.y;
        v.z = acc[hi*4+i][hj*4+2] + bb.z;
        v.w = acc[hi*4+i][hj*4+3] + bb.w;
        *(float4*)(C + (size_t)m * N + n) = v;
      }
    }
}

// ---------------------------------------------------------------------------
// Persistent GRU recurrence. 128 blocks x 256 threads, all co-resident.
// Block g owns hidden units j0=g*4 .. j0+3 (12 w_hh rows in LDS) for all 16
// batches. Per step: stage h (agent-coherent loads), 512-long dots, gates,
// publish h_new (agent stores), monotonic global barrier.
// ---------------------------------------------------------------------------
__global__ __launch_bounds__(256)
void gru_rec(const float* __restrict__ xp,     // [B,T,1536]
             const float* __restrict__ w_hh,   // [1536,512]
             const float* __restrict__ b_hh,   // [1536]
             float* __restrict__ hbuf,         // [2][16][512] ws
             unsigned* __restrict__ cnt,       // zeroed barrier counter
             float* __restrict__ out,          // [B,T,512]
             int apply_gelu) {
  __shared__ float w_s[12][516];
  __shared__ float h_s[16][516];
  __shared__ float gh_s[12 * 17];
  __shared__ float xq_s[192];     // [b][gate][u]
  __shared__ float bhh_s[12];

  int tid = threadIdx.x;
  int j0 = blockIdx.x * SU;

  // stage this block's 12 w_hh rows (row order: r gate 0..3 = units, z 4..7, n 8..11)
  for (int idx = tid; idx < 12 * 128; idx += 256) {
    int r = idx >> 7;
    int kc = idx & 127;
    int gate = r >> 2, u = r & 3;
    int row = gate * 512 + j0 + u;
    float4 v = *(const float4*)(w_hh + (size_t)row * KDIM + kc * 4);
    *(float4*)&w_s[r][kc * 4] = v;
  }
  if (tid < 12) {
    int gate = tid >> 2, u = tid & 3;
    bhh_s[tid] = b_hh[gate * 512 + j0 + u];
  }
  __syncthreads();

  int r = tid >> 4;   // 0..15, rows 0..11 active
  int b = tid & 15;

  for (int t = 0; t < TLEN; t++) {
    // ---- stage h(t-1) into LDS ----
    if (t == 0) {
      for (int idx = tid; idx < 16 * 512; idx += 256)
        h_s[idx >> 9][idx & 511] = 0.f;
    } else {
      const float* hr = hbuf + ((t + 1) & 1) * (16 * 512);
      for (int idx = tid; idx < 16 * 512; idx += 256) {
        unsigned uv = __hip_atomic_load((const unsigned*)(hr + idx),
                                        __ATOMIC_RELAXED, __HIP_MEMORY_SCOPE_AGENT);
        h_s[idx >> 9][idx & 511] = __uint_as_float(uv);
      }
    }
    // ---- stage xp slice: 16 b x 3 gates x 4 units ----
    if (tid < 48) {
      int bb = tid / 3, g = tid % 3;
      const float* p = xp + ((size_t)(bb * TLEN + t)) * G3 + g * 512 + j0;
      *(float4*)&xq_s[tid * 4] = *(const float4*)p;   // layout [(bb*3+g)*4 + u]
    }
    __syncthreads();

    // ---- gh = h @ w_hh_slice^T  (192 threads: one (row,batch) each) ----
    if (tid < 192) {
      float4 acc = {0.f, 0.f, 0.f, 0.f};
#pragma unroll 8
      for (int kc = 0; kc < 128; kc++) {
        float4 w4 = *(const float4*)&w_s[r][kc * 4];
        float4 h4 = *(const float4*)&h_s[b][kc * 4];
        acc.x += w4.x * h4.x; acc.y += w4.y * h4.y;
        acc.z += w4.z * h4.z; acc.w += w4.w * h4.w;
      }
      gh_s[r * 17 + b] = (acc.x + acc.y) + (acc.z + acc.w) + bhh_s[r];
    }
    __syncthreads();

    // ---- gates + h update (64 threads: 4 units x 16 batches) ----
    if (tid < 64) {
      int u = tid >> 4, bb = tid & 15;
      float xr = xq_s[(bb * 3 + 0) * 4 + u];
      float xz = xq_s[(bb * 3 + 1) * 4 + u];
      float xn = xq_s[(bb * 3 + 2) * 4 + u];
      float ghr = gh_s[(0 + u) * 17 + bb];
      float ghz = gh_s[(4 + u) * 17 + bb];
      float ghn = gh_s[(8 + u) * 17 + bb];
      float rg = 1.f / (1.f + expf(-(xr + ghr)));
      float zg = 1.f / (1.f + expf(-(xz + ghz)));
      float ng = tanhf(xn + rg * ghn);
      float hold = h_s[bb][j0 + u];
      float hn = (1.f - zg) * ng + zg * hold;
      float* hw = hbuf + (t & 1) * (16 * 512);
      __hip_atomic_store((unsigned*)(hw + bb * 512 + j0 + u), __float_as_uint(hn),
                         __ATOMIC_RELAXED, __HIP_MEMORY_SCOPE_AGENT);
      float ov = hn;
      if (apply_gelu) ov = 0.5f * hn * (1.f + erff(hn * 0.70710678118654752f));
      out[((size_t)(bb * TLEN + t)) * 512 + j0 + u] = ov;
    }

    // ---- grid barrier (monotonic counter, release/acquire agent scope) ----
    __syncthreads();
    if (tid == 0) {
      __hip_atomic_fetch_add(cnt, 1u, __ATOMIC_RELEASE, __HIP_MEMORY_SCOPE_AGENT);
      unsigned target = (unsigned)(t + 1) * GRID_REC;
      while (__hip_atomic_load(cnt, __ATOMIC_ACQUIRE, __HIP_MEMORY_SCOPE_AGENT) < target)
        __builtin_amdgcn_s_sleep(1);
    }
    __syncthreads();
  }
}

// ---------------------------------------------------------------------------
// ws layout: [0, 402.65MB) xp   | hbuf 64KB | barrier counters 256B
// gelu(h1) is staged in d_out between the two layers (rec2 only reads xp).
// ---------------------------------------------------------------------------
extern "C" void kernel_launch(void* const* d_in, const int* in_sizes, int n_in,
                              void* d_out, int out_size, void* d_ws, size_t ws_size,
                              hipStream_t stream) {
  const float* x     = (const float*)d_in[0];
  const float* w_ih1 = (const float*)d_in[1];
  const float* w_hh1 = (const float*)d_in[2];
  const float* b_ih1 = (const float*)d_in[3];
  const float* b_hh1 = (const float*)d_in[4];
  const float* w_ih2 = (const float*)d_in[5];
  const float* w_hh2 = (const float*)d_in[6];
  const float* b_ih2 = (const float*)d_in[7];
  const float* b_hh2 = (const float*)d_in[8];
  float* y = (float*)d_out;

  char* ws = (char*)d_ws;
  const size_t XPB = (size_t)BATCH * TLEN * G3 * sizeof(float);  // 402,653,184
  float*    xp   = (float*)ws;
  float*    hbuf = (float*)(ws + XPB);
  unsigned* cnts = (unsigned*)(ws + XPB + 2 * 16 * 512 * sizeof(float));

  hipMemsetAsync(cnts, 0, 256, stream);

  dim3 gg(12, 512), tb(256);
  const int M = BATCH * TLEN;  // 65536

  gemm_nt_bias<<<gg, tb, 0, stream>>>(x, w_ih1, b_ih1, xp, M, G3);
  gru_rec<<<dim3(GRID_REC), tb, 0, stream>>>(xp, w_hh1, b_hh1, hbuf, cnts + 0, y, 1);
  gemm_nt_bias<<<gg, tb, 0, stream>>>(y, w_ih2, b_ih2, xp, M, G3);
  gru_rec<<<dim3(GRID_REC), tb, 0, stream>>>(xp, w_hh2, b_hh2, hbuf, cnts + 32, y, 0);
}

// Round 2
// 87998.877 us; speedup vs baseline: 1.6311x; 1.6311x over previous
//
#include <hip/hip_runtime.h>
#include <math.h>

#define BATCH 16
#define TLEN 4096
#define KDIM 512
#define G3 1536

// recurrence partition
#define UB 32            // unit-group blocks (16 units each)
#define BB 4             // batch-group blocks (4 batches each)
#define NBLK (UB * BB)   // 128 persistent blocks
#define UPB 16           // units per block
#define BPB 4            // batches per block
#define ROWS 48          // 3 gates * UPB
#define REC_THREADS 384  // 12 tiles * 32 k-splits

#define WP 516           // w_s row pitch (floats)
#define HP 516           // h_s row pitch
#define PP 36            // partials row pitch (32 + 4, float4-aligned)

#define W_OFF 0
#define H_OFF (ROWS * WP)                    // 24768
#define PART_OFF (H_OFF + BPB * HP)          // 26832
#define GH_OFF (PART_OFF + 12 * 16 * PP)     // 33744
#define XQ_OFF (GH_OFF + ROWS * BPB)         // 33936
#define BH_OFF (XQ_OFF + 3 * BPB * UPB)      // 34128
#define SMEM_FLOATS (BH_OFF + ROWS)          // 34176
#define SMEM_BYTES (SMEM_FLOATS * 4)         // 136704 B (< 160 KiB)

// ---------------------------------------------------------------------------
// GEMM: xp_t = A[M,K] @ W[N,K]^T + bias, written in recurrence-friendly
// transposed layout: xp_t[t][ublock(32)][bblock(4)][gate(3)][b_in(4)][u_in(16)]
// so each rec block reads one contiguous 768B slice per step.
// ---------------------------------------------------------------------------
__global__ __launch_bounds__(256)
void gemm_nt_bias(const float* __restrict__ A, const float* __restrict__ W,
                  const float* __restrict__ bias, float* __restrict__ C,
                  int M, int N) {
  const int K = KDIM;
  __shared__ float As[16][132];
  __shared__ float Bs[16][132];
  int tid = threadIdx.x;
  int tx = tid & 15, ty = tid >> 4;
  int bx = blockIdx.x, by = blockIdx.y;
  const float* Ab = A + (size_t)by * 128 * K;
  const float* Wb = W + (size_t)bx * 128 * K;

  float acc[8][8];
#pragma unroll
  for (int i = 0; i < 8; i++)
#pragma unroll
    for (int j = 0; j < 8; j++) acc[i][j] = 0.f;

  for (int kk = 0; kk < K; kk += 16) {
    __syncthreads();
#pragma unroll
    for (int i = 0; i < 2; i++) {
      int task = tid + i * 256;
      int kc = task & 3;
      int m = task >> 2;
      float4 va = *(const float4*)(Ab + (size_t)m * K + kk + kc * 4);
      As[kc*4+0][m] = va.x; As[kc*4+1][m] = va.y;
      As[kc*4+2][m] = va.z; As[kc*4+3][m] = va.w;
      float4 vb = *(const float4*)(Wb + (size_t)m * K + kk + kc * 4);
      Bs[kc*4+0][m] = vb.x; Bs[kc*4+1][m] = vb.y;
      Bs[kc*4+2][m] = vb.z; Bs[kc*4+3][m] = vb.w;
    }
    __syncthreads();
#pragma unroll
    for (int k = 0; k < 16; k++) {
      float4 a0 = *(const float4*)&As[k][ty * 4];
      float4 a1 = *(const float4*)&As[k][64 + ty * 4];
      float4 b0 = *(const float4*)&Bs[k][tx * 4];
      float4 b1 = *(const float4*)&Bs[k][64 + tx * 4];
      float av[8] = {a0.x, a0.y, a0.z, a0.w, a1.x, a1.y, a1.z, a1.w};
      float bv[8] = {b0.x, b0.y, b0.z, b0.w, b1.x, b1.y, b1.z, b1.w};
#pragma unroll
      for (int i = 0; i < 8; i++)
#pragma unroll
        for (int j = 0; j < 8; j++) acc[i][j] += av[i] * bv[j];
    }
  }

#pragma unroll
  for (int hi = 0; hi < 2; hi++)
#pragma unroll
    for (int i = 0; i < 4; i++) {
      int m = by * 128 + hi * 64 + ty * 4 + i;
      int b = m >> 12;           // m / TLEN
      int t = m & (TLEN - 1);
#pragma unroll
      for (int hj = 0; hj < 2; hj++) {
        int n = bx * 128 + hj * 64 + tx * 4;
        int g = n >> 9;          // gate
        int unit = n & 511;
        float4 bb = *(const float4*)(bias + n);
        float4 v;
        v.x = acc[hi*4+i][hj*4+0] + bb.x;
        v.y = acc[hi*4+i][hj*4+1] + bb.y;
        v.z = acc[hi*4+i][hj*4+2] + bb.z;
        v.w = acc[hi*4+i][hj*4+3] + bb.w;
        // xp_t[t][unit>>4][b>>2][g][b&3][unit&15]
        size_t dst = ((((size_t)t * UB + (unit >> 4)) * BB + (b >> 2)) * 3 + g) * (BPB * UPB)
                     + (b & 3) * UPB + (unit & 15);
        *(float4*)(C + dst) = v;
      }
    }
}

// ---------------------------------------------------------------------------
// Persistent GRU recurrence. Grid (32 ublocks, 4 bblocks) = 128 blocks,
// 384 threads, 136.7 KB dynamic LDS, 1 block/CU, all co-resident.
// ---------------------------------------------------------------------------
__global__ __launch_bounds__(REC_THREADS, 1)
void gru_rec(const float* __restrict__ xp,     // transposed layout (see gemm)
             const float* __restrict__ w_hh,   // [1536,512]
             const float* __restrict__ b_hh,   // [1536]
             float* __restrict__ hbuf,         // [2][16][512]
             unsigned* __restrict__ cnt,
             float* __restrict__ out,          // [B,T,512]
             int apply_gelu) {
  extern __shared__ float sm[];
  float* w_s   = sm + W_OFF;     // [48][WP]
  float* h_s   = sm + H_OFF;     // [4][HP]  full h(t-1) for this block's batches
  float* part_s= sm + PART_OFF;  // [12*16][PP]
  float* gh_s  = sm + GH_OFF;    // [48*4]  (r*4+b)
  float* xq_s  = sm + XQ_OFF;    // [3][4][16] = [g][b][u]
  float* bhh_s = sm + BH_OFF;    // [48]

  const int tid = threadIdx.x;
  const int u0 = blockIdx.x * UPB;
  const int b0 = blockIdx.y * BPB;
  const float* xslice = xp + ((size_t)blockIdx.x * BB + blockIdx.y) * (3 * BPB * UPB);

  // ---- stage w rows: r = gate*16+u  <->  global row gate*512+u0+u ----
  for (int idx = tid; idx < ROWS * 128; idx += REC_THREADS) {
    int r = idx >> 7, k4 = idx & 127;
    int gate = r >> 4, u = r & 15;
    float4 v = *(const float4*)(w_hh + (size_t)(gate * KDIM + u0 + u) * KDIM + k4 * 4);
    *(float4*)(w_s + r * WP + k4 * 4) = v;
  }
  if (tid < ROWS) bhh_s[tid] = b_hh[(tid >> 4) * KDIM + u0 + (tid & 15)];

  // prefetch x-slice for t=0 (one contiguous 768B chunk, 48 float4)
  float4 xq_reg = {0.f, 0.f, 0.f, 0.f};
  if (tid < 48) xq_reg = *(const float4*)(xslice + tid * 4);
  __syncthreads();

  const int tile = tid >> 5;   // 0..11 (4-row tiles)
  const int ks = tid & 31;     // k-split lane

  for (int t = 0; t < TLEN; t++) {
    // ---- stage h(t-1) [4 batches x 512] ----
    if (t == 0) {
      for (int idx = tid; idx < BPB * KDIM; idx += REC_THREADS)
        h_s[(idx >> 9) * HP + (idx & 511)] = 0.f;
    } else {
      const float* hr = hbuf + ((t + 1) & 1) * (BATCH * KDIM);
      for (int idx = tid; idx < BPB * 128; idx += REC_THREADS) {
        int b = idx >> 7, k4 = idx & 127;
        float4 v = *(const float4*)(hr + (size_t)(b0 + b) * KDIM + k4 * 4);
        *(float4*)(h_s + b * HP + k4 * 4) = v;
      }
    }
    // publish this step's x-slice from the prefetch register
    if (tid < 48) *(float4*)(xq_s + tid * 4) = xq_reg;
    __syncthreads();

    // issue prefetch for t+1 (completes well before it's consumed next iter)
    if (tid < 48 && t + 1 < TLEN)
      xq_reg = *(const float4*)(xslice + (size_t)(t + 1) * (UB * BB * 3 * BPB * UPB) + tid * 4);

    // ---- dots: 4 rows x 4 batches per thread, k-interleaved split ----
    float4 a00={0,0,0,0},a01={0,0,0,0},a02={0,0,0,0},a03={0,0,0,0};
    float4 a10={0,0,0,0},a11={0,0,0,0},a12={0,0,0,0},a13={0,0,0,0};
    float4 a20={0,0,0,0},a21={0,0,0,0},a22={0,0,0,0},a23={0,0,0,0};
    float4 a30={0,0,0,0},a31={0,0,0,0},a32={0,0,0,0},a33={0,0,0,0};
#pragma unroll
    for (int kk = 0; kk < 4; kk++) {
      int k4 = kk * 32 + ks;           // float4 index, lane-consecutive
      float4 h0v = *(const float4*)(h_s + 0 * HP + k4 * 4);
      float4 h1v = *(const float4*)(h_s + 1 * HP + k4 * 4);
      float4 h2v = *(const float4*)(h_s + 2 * HP + k4 * 4);
      float4 h3v = *(const float4*)(h_s + 3 * HP + k4 * 4);
      float4 w0v = *(const float4*)(w_s + (tile * 4 + 0) * WP + k4 * 4);
      float4 w1v = *(const float4*)(w_s + (tile * 4 + 1) * WP + k4 * 4);
      float4 w2v = *(const float4*)(w_s + (tile * 4 + 2) * WP + k4 * 4);
      float4 w3v = *(const float4*)(w_s + (tile * 4 + 3) * WP + k4 * 4);
#define FMA4(d, wv, hv) d.x += wv.x*hv.x; d.y += wv.y*hv.y; d.z += wv.z*hv.z; d.w += wv.w*hv.w;
      FMA4(a00, w0v, h0v) FMA4(a01, w0v, h1v) FMA4(a02, w0v, h2v) FMA4(a03, w0v, h3v)
      FMA4(a10, w1v, h0v) FMA4(a11, w1v, h1v) FMA4(a12, w1v, h2v) FMA4(a13, w1v, h3v)
      FMA4(a20, w2v, h0v) FMA4(a21, w2v, h1v) FMA4(a22, w2v, h2v) FMA4(a23, w2v, h3v)
      FMA4(a30, w3v, h0v) FMA4(a31, w3v, h1v) FMA4(a32, w3v, h2v) FMA4(a33, w3v, h3v)
#undef FMA4
    }
    {
      float* pb = part_s + (size_t)tile * 16 * PP + ks;
#define HS(v) ((v.x + v.y) + (v.z + v.w))
      pb[(0*4+0)*PP] = HS(a00); pb[(0*4+1)*PP] = HS(a01); pb[(0*4+2)*PP] = HS(a02); pb[(0*4+3)*PP] = HS(a03);
      pb[(1*4+0)*PP] = HS(a10); pb[(1*4+1)*PP] = HS(a11); pb[(1*4+2)*PP] = HS(a12); pb[(1*4+3)*PP] = HS(a13);
      pb[(2*4+0)*PP] = HS(a20); pb[(2*4+1)*PP] = HS(a21); pb[(2*4+2)*PP] = HS(a22); pb[(2*4+3)*PP] = HS(a23);
      pb[(3*4+0)*PP] = HS(a30); pb[(3*4+1)*PP] = HS(a31); pb[(3*4+2)*PP] = HS(a32); pb[(3*4+3)*PP] = HS(a33);
#undef HS
    }
    __syncthreads();

    // ---- reduce 32 k-split partials -> gh (threads 0..191, p = r*4+b = tid) ----
    if (tid < 192) {
      const float* p = part_s + (size_t)tid * PP;
      float4 s0 = *(const float4*)(p + 0);
      float4 s1 = *(const float4*)(p + 4);
      float4 s2 = *(const float4*)(p + 8);
      float4 s3 = *(const float4*)(p + 12);
      float4 s4 = *(const float4*)(p + 16);
      float4 s5 = *(const float4*)(p + 20);
      float4 s6 = *(const float4*)(p + 24);
      float4 s7 = *(const float4*)(p + 28);
      float4 ss;
      ss.x = s0.x + s1.x + s2.x + s3.x + s4.x + s5.x + s6.x + s7.x;
      ss.y = s0.y + s1.y + s2.y + s3.y + s4.y + s5.y + s6.y + s7.y;
      ss.z = s0.z + s1.z + s2.z + s3.z + s4.z + s5.z + s6.z + s7.z;
      ss.w = s0.w + s1.w + s2.w + s3.w + s4.w + s5.w + s6.w + s7.w;
      gh_s[tid] = (ss.x + ss.y) + (ss.z + ss.w) + bhh_s[tid >> 2];
    }
    __syncthreads();

    // ---- gates + h update (64 threads: u = tid&15, b = tid>>4) ----
    if (tid < 64) {
      int u = tid & 15, b = tid >> 4;
      float xr = xq_s[0 * 64 + b * 16 + u];
      float xz = xq_s[1 * 64 + b * 16 + u];
      float xn = xq_s[2 * 64 + b * 16 + u];
      float ghr = gh_s[(0 * 16 + u) * 4 + b];
      float ghz = gh_s[(1 * 16 + u) * 4 + b];
      float ghn = gh_s[(2 * 16 + u) * 4 + b];
      float rg = 1.f / (1.f + expf(-(xr + ghr)));
      float zg = 1.f / (1.f + expf(-(xz + ghz)));
      float ng = tanhf(xn + rg * ghn);
      float hold = h_s[b * HP + u0 + u];
      float hn = (1.f - zg) * ng + zg * hold;
      hbuf[(t & 1) * (BATCH * KDIM) + (size_t)(b0 + b) * KDIM + u0 + u] = hn;
      float ov = hn;
      if (apply_gelu) ov = 0.5f * hn * (1.f + erff(hn * 0.70710678118654752f));
      out[((size_t)((b0 + b) * TLEN + t)) * KDIM + u0 + u] = ov;
    }

    // ---- grid barrier: drain stores, release, add, spin, acquire ----
    __syncthreads();   // compiler drains vmcnt before s_barrier
    if (tid == 0) {
      __threadfence();  // agent-scope release: writeback L2 -> visible to all XCDs
      __hip_atomic_fetch_add(cnt, 1u, __ATOMIC_RELAXED, __HIP_MEMORY_SCOPE_AGENT);
      unsigned target = (unsigned)(t + 1) * NBLK;
      while (__hip_atomic_load(cnt, __ATOMIC_RELAXED, __HIP_MEMORY_SCOPE_AGENT) < target)
        __builtin_amdgcn_s_sleep(1);
      __threadfence();  // agent-scope acquire: invalidate L1/L2 before h reloads
    }
    __syncthreads();
  }
}

// ---------------------------------------------------------------------------
// ws layout: [0, 402.65MB) xp_t | hbuf 64KB | barrier counters 256B
// ---------------------------------------------------------------------------
extern "C" void kernel_launch(void* const* d_in, const int* in_sizes, int n_in,
                              void* d_out, int out_size, void* d_ws, size_t ws_size,
                              hipStream_t stream) {
  const float* x     = (const float*)d_in[0];
  const float* w_ih1 = (const float*)d_in[1];
  const float* w_hh1 = (const float*)d_in[2];
  const float* b_ih1 = (const float*)d_in[3];
  const float* b_hh1 = (const float*)d_in[4];
  const float* w_ih2 = (const float*)d_in[5];
  const float* w_hh2 = (const float*)d_in[6];
  const float* b_ih2 = (const float*)d_in[7];
  const float* b_hh2 = (const float*)d_in[8];
  float* y = (float*)d_out;

  char* ws = (char*)d_ws;
  const size_t XPB = (size_t)BATCH * TLEN * G3 * sizeof(float);
  float*    xp   = (float*)ws;
  float*    hbuf = (float*)(ws + XPB);
  unsigned* cnts = (unsigned*)(ws + XPB + (size_t)2 * BATCH * KDIM * sizeof(float));

  hipFuncSetAttribute((const void*)gru_rec,
                      hipFuncAttributeMaxDynamicSharedMemorySize, SMEM_BYTES);
  hipMemsetAsync(cnts, 0, 256, stream);

  dim3 gg(12, 512), tb(256);
  const int M = BATCH * TLEN;

  gemm_nt_bias<<<gg, tb, 0, stream>>>(x, w_ih1, b_ih1, xp, M, G3);
  gru_rec<<<dim3(UB, BB), REC_THREADS, SMEM_BYTES, stream>>>(xp, w_hh1, b_hh1, hbuf, cnts + 0, y, 1);
  gemm_nt_bias<<<gg, tb, 0, stream>>>(y, w_ih2, b_ih2, xp, M, G3);
  gru_rec<<<dim3(UB, BB), REC_THREADS, SMEM_BYTES, stream>>>(xp, w_hh2, b_hh2, hbuf, cnts + 32, y, 0);
}